// Round 10
// baseline (59.561 us; speedup 1.0000x reference)
//
#include <hip/hip_runtime.h>
#include <stdint.h>

// Problem constants (from reference setup_inputs): B=32, T=4096, C=256.
#define BB 32
#define TT 4096
#define CC 256
#define BT (BB * TT)

#define NBLK 2048   // grid-stride resident blocks for argmax / mean

typedef float f32x4 __attribute__((ext_vector_type(4)));

// ---------------------------------------------------------------------------
// Kernel A: per-frame argmax over C=256 -> preds_raw[b*T+t] (mask NOT applied).
// Grid-stride, 1 wave per row, 8 rows unrolled (8 independent load chains,
// 8 KB in flight per wave). Ballot reduce (verified bit-exact R6-R9).
// ---------------------------------------------------------------------------
__global__ __launch_bounds__(256) void argmax_kernel(
    const float* __restrict__ logits,
    int* __restrict__ preds_raw) {
  const int lane   = threadIdx.x & 63;
  const int gwave  = (int)((blockIdx.x * blockDim.x + threadIdx.x) >> 6);
  const int nwaves = (int)((gridDim.x * blockDim.x) >> 6);   // 8192

  for (int row = gwave * 8; row < BT; row += nwaves * 8) {
    float4 v[8];
    #pragma unroll
    for (int r = 0; r < 8; ++r)
      v[r] = reinterpret_cast<const float4*>(logits + (size_t)(row + r) * CC)[lane];

    float m[8]; int idx[8];
    #pragma unroll
    for (int r = 0; r < 8; ++r) {
      float mm = v[r].x; int ii = 0;
      if (v[r].y > mm) { mm = v[r].y; ii = 1; }
      if (v[r].z > mm) { mm = v[r].z; ii = 2; }
      if (v[r].w > mm) { mm = v[r].w; ii = 3; }
      m[r] = mm; idx[r] = ii;
    }

    float w[8];
    #pragma unroll
    for (int r = 0; r < 8; ++r) w[r] = m[r];
    #pragma unroll
    for (int off = 1; off < 64; off <<= 1) {
      #pragma unroll
      for (int r = 0; r < 8; ++r)
        w[r] = fmaxf(w[r], __shfl_xor(w[r], off));
    }

    int c[8];
    #pragma unroll
    for (int r = 0; r < 8; ++r) {
      unsigned long long bl = __ballot(m[r] == w[r]);
      int s = __ffsll(bl) - 1;
      c[r] = __shfl(idx[r], s) + s * 4;
    }

    if (lane == 0) {
      int4 c0 = make_int4(c[0], c[1], c[2], c[3]);
      int4 c1 = make_int4(c[4], c[5], c[6], c[7]);
      *reinterpret_cast<int4*>(preds_raw + row)     = c0;
      *reinterpret_cast<int4*>(preds_raw + row + 4) = c1;
    }
  }
}

// ---------------------------------------------------------------------------
// Kernel B (R5-proven, unchanged except plain pad store): mask-dtype detect +
// mask apply + RLE segmentation + compaction via 2-level shfl scan.
// ---------------------------------------------------------------------------
__global__ __launch_bounds__(1024) void seg_kernel(
    const int* __restrict__ preds_raw,
    const unsigned char* __restrict__ mask8,
    const int* __restrict__ mask32,
    uint32_t* __restrict__ seg_info,
    int* __restrict__ n_keep,
    float* __restrict__ pad_out) {
  const int b    = blockIdx.x;
  const int tid  = threadIdx.x;          // 0..1023, each owns 4 positions
  const int lane = tid & 63;
  const int wid  = tid >> 6;             // 16 waves

  __shared__ int sp[TT];
  __shared__ int wsum[16];
  __shared__ int mdet;

  // ---- mask layout detection: int32 0/1 => every byte at %4!=0 is zero ----
  if (tid == 0) mdet = 0;
  __syncthreads();
  {
    uchar4 mv = reinterpret_cast<const uchar4*>(mask8)[tid];  // bytes [0,4096)
    if (mv.y | mv.z | mv.w) atomicOr(&mdet, 1);
  }
  __syncthreads();
  const bool is_u8 = (mdet != 0);

  // ---- stage masked preds for this batch ----
  int4 pv = reinterpret_cast<const int4*>(preds_raw + (size_t)b * TT)[tid];
  int m0, m1, m2, m3;
  if (is_u8) {
    uchar4 mv = reinterpret_cast<const uchar4*>(mask8 + (size_t)b * TT)[tid];
    m0 = mv.x; m1 = mv.y; m2 = mv.z; m3 = mv.w;
  } else {
    int4 mv = reinterpret_cast<const int4*>(mask32 + (size_t)b * TT)[tid];
    m0 = mv.x; m1 = mv.y; m2 = mv.z; m3 = mv.w;
  }
  sp[tid * 4 + 0] = m0 ? -1 : pv.x;
  sp[tid * 4 + 1] = m1 ? -1 : pv.y;
  sp[tid * 4 + 2] = m2 ? -1 : pv.z;
  sp[tid * 4 + 3] = m3 ? -1 : pv.w;
  __syncthreads();

  // ---- kept-segment-start flags for my 4 positions ----
  int kb[4]; int cnt = 0;
  #pragma unroll
  for (int j = 0; j < 4; ++j) {
    int t = tid * 4 + j;
    int p = sp[t];
    int isStart = (p != -1) && (t == 0 || p != sp[t - 1]);
    kb[j] = isStart;
    cnt += isStart;
  }

  // ---- 2-level exclusive scan: intra-wave shfl_up, then 16 wave totals ----
  int inc = cnt;
  #pragma unroll
  for (int off = 1; off < 64; off <<= 1) {
    int v = __shfl_up(inc, off);
    if (lane >= off) inc += v;
  }
  if (lane == 63) wsum[wid] = inc;
  __syncthreads();
  int woff = 0, total = 0;
  #pragma unroll
  for (int i = 0; i < 16; ++i) {
    int w = wsum[i];
    if (i < wid) woff += w;
    total += w;
  }
  int k = woff + (inc - cnt);            // exclusive prefix -> my first dest

  // ---- emit seg_info for kept segments I own ----
  #pragma unroll
  for (int j = 0; j < 4; ++j) {
    if (kb[j]) {
      int t = tid * 4 + j;
      int p = sp[t];
      int len = 1;
      while (t + len < TT && sp[t + len] == p) ++len;
      seg_info[(size_t)b * TT + k] = (uint32_t)t | ((uint32_t)len << 16);
      ++k;
    }
  }

  if (tid == 0) n_keep[b] = total;

  // ---- new_pad output: t >= n_keep -> 1.0f else 0.0f ----
  f32x4 pw;
  int t0 = tid * 4;
  pw.x = (t0 + 0 >= total) ? 1.0f : 0.0f;
  pw.y = (t0 + 1 >= total) ? 1.0f : 0.0f;
  pw.z = (t0 + 2 >= total) ? 1.0f : 0.0f;
  pw.w = (t0 + 3 >= total) ? 1.0f : 0.0f;
  reinterpret_cast<f32x4*>(pad_out + (size_t)b * TT)[tid] = pw;
}

// ---------------------------------------------------------------------------
// Kernel C: segment means scattered to compacted rows; zeros elsewhere.
// Grid-stride, 1 wave per output row, 4 rows unrolled. PLAIN stores this
// round (A/B vs R9's nt stores: fills hit 6.9-7.1 TB/s with plain stores).
// ---------------------------------------------------------------------------
__global__ __launch_bounds__(256) void mean_kernel(
    const float* __restrict__ logits,
    const uint32_t* __restrict__ seg_info,
    const int* __restrict__ n_keep,
    float* __restrict__ out) {
  const int lane   = threadIdx.x & 63;
  const int gwave  = (int)((blockIdx.x * blockDim.x + threadIdx.x) >> 6);
  const int nwaves = (int)((gridDim.x * blockDim.x) >> 6);   // 8192

  for (int row = gwave * 4; row < BT; row += nwaves * 4) {
    // row % 4 == 0 and TT % 4 == 0 -> all 4 rows share a batch
    const int b  = row >> 12;
    const int nk = n_keep[b];
    const int kbase = row & (TT - 1);

    uint32_t info[4];
    #pragma unroll
    for (int r = 0; r < 4; ++r)
      info[r] = (kbase + r < nk) ? seg_info[row + r] : 0u;

    f32x4 res[4];
    #pragma unroll
    for (int r = 0; r < 4; ++r) {
      res[r] = (f32x4)0.0f;
      if (kbase + r < nk) {
        int start = (int)(info[r] & 0xFFFFu), len = (int)(info[r] >> 16);
        const float4* g =
            reinterpret_cast<const float4*>(logits + ((size_t)b * TT + start) * CC) + lane;
        float4 s = make_float4(0.f, 0.f, 0.f, 0.f);
        for (int j = 0; j < len; ++j) {
          float4 vv = g[(size_t)j * (CC / 4)];
          s.x += vv.x; s.y += vv.y; s.z += vv.z; s.w += vv.w;
        }
        float inv = 1.0f / (float)len;
        res[r].x = s.x * inv; res[r].y = s.y * inv;
        res[r].z = s.z * inv; res[r].w = s.w * inv;
      }
    }

    #pragma unroll
    for (int r = 0; r < 4; ++r)
      reinterpret_cast<f32x4*>(out + (size_t)(row + r) * CC)[lane] = res[r];
  }
}

// ---------------------------------------------------------------------------
extern "C" void kernel_launch(void* const* d_in, const int* in_sizes, int n_in,
                              void* d_out, int out_size, void* d_ws, size_t ws_size,
                              hipStream_t stream) {
  const float* logits        = (const float*)d_in[0];
  const unsigned char* mask8 = (const unsigned char*)d_in[1];
  const int* mask32          = (const int*)d_in[1];

  float* out_logits = (float*)d_out;                       // [B,T,C]
  float* out_pad    = (float*)d_out + (size_t)BT * CC;     // [B,T] as float 0/1

  // workspace layout
  int*      preds    = (int*)d_ws;                               // B*T int32
  uint32_t* seg_info = (uint32_t*)((char*)d_ws + (size_t)BT*4);  // B*T u32
  int*      nkeep    = (int*)((char*)d_ws + (size_t)BT*8);       // B int32

  argmax_kernel<<<NBLK, 256, 0, stream>>>(logits, preds);
  seg_kernel<<<BB, 1024, 0, stream>>>(preds, mask8, mask32, seg_info, nkeep, out_pad);
  mean_kernel<<<NBLK, 256, 0, stream>>>(logits, seg_info, nkeep, out_logits);
}

// Round 11
// 58.471 us; speedup vs baseline: 1.0186x; 1.0186x over previous
//
#include <hip/hip_runtime.h>
#include <stdint.h>

// Problem constants (from reference setup_inputs): B=32, T=4096, C=256.
#define BB 32
#define TT 4096
#define CC 256
#define BT (BB * TT)

#define NBLK 2048   // grid-stride resident blocks for argmax / mean

typedef float f32x4 __attribute__((ext_vector_type(4)));

// ---------------------------------------------------------------------------
// Kernel A: per-frame argmax over C=256 -> preds_raw[b*T+t] (mask NOT applied).
// Grid-stride, 1 wave per row, 4 rows unrolled (4 independent load chains).
// Ballot reduce: wave fmax, then lowest lane holding the max gives the lowest
// channel (strict > in the per-lane step keeps lowest channel on ties) —
// matches jnp.argmax first-index tie-break. Verified bit-exact R6-R10.
// ---------------------------------------------------------------------------
__global__ __launch_bounds__(256) void argmax_kernel(
    const float* __restrict__ logits,
    int* __restrict__ preds_raw) {
  const int lane   = threadIdx.x & 63;
  const int gwave  = (int)((blockIdx.x * blockDim.x + threadIdx.x) >> 6);
  const int nwaves = (int)((gridDim.x * blockDim.x) >> 6);   // 8192

  for (int row = gwave * 4; row < BT; row += nwaves * 4) {
    float4 v[4];
    #pragma unroll
    for (int r = 0; r < 4; ++r)
      v[r] = reinterpret_cast<const float4*>(logits + (size_t)(row + r) * CC)[lane];

    float m[4]; int idx[4];
    #pragma unroll
    for (int r = 0; r < 4; ++r) {
      float mm = v[r].x; int ii = 0;
      if (v[r].y > mm) { mm = v[r].y; ii = 1; }
      if (v[r].z > mm) { mm = v[r].z; ii = 2; }
      if (v[r].w > mm) { mm = v[r].w; ii = 3; }
      m[r] = mm; idx[r] = ii;
    }

    float w[4] = {m[0], m[1], m[2], m[3]};
    #pragma unroll
    for (int off = 1; off < 64; off <<= 1) {
      #pragma unroll
      for (int r = 0; r < 4; ++r)
        w[r] = fmaxf(w[r], __shfl_xor(w[r], off));
    }

    int4 c;
    {
      unsigned long long bl0 = __ballot(m[0] == w[0]);
      unsigned long long bl1 = __ballot(m[1] == w[1]);
      unsigned long long bl2 = __ballot(m[2] == w[2]);
      unsigned long long bl3 = __ballot(m[3] == w[3]);
      int s0 = __ffsll(bl0) - 1, s1 = __ffsll(bl1) - 1;
      int s2 = __ffsll(bl2) - 1, s3 = __ffsll(bl3) - 1;
      c.x = __shfl(idx[0], s0) + s0 * 4;
      c.y = __shfl(idx[1], s1) + s1 * 4;
      c.z = __shfl(idx[2], s2) + s2 * 4;
      c.w = __shfl(idx[3], s3) + s3 * 4;
    }

    if (lane == 0)
      *reinterpret_cast<int4*>(preds_raw + row) = c;
  }
}

// ---------------------------------------------------------------------------
// Kernel B (R5-proven, unchanged): mask-dtype detect + mask apply + RLE
// segmentation + stream-compaction via 2-level shfl scan. One 1024-thread
// block per batch; masked preds staged in LDS. seg_info packs (start|len<<16).
// ---------------------------------------------------------------------------
__global__ __launch_bounds__(1024) void seg_kernel(
    const int* __restrict__ preds_raw,
    const unsigned char* __restrict__ mask8,
    const int* __restrict__ mask32,
    uint32_t* __restrict__ seg_info,
    int* __restrict__ n_keep,
    float* __restrict__ pad_out) {
  const int b    = blockIdx.x;
  const int tid  = threadIdx.x;          // 0..1023, each owns 4 positions
  const int lane = tid & 63;
  const int wid  = tid >> 6;             // 16 waves

  __shared__ int sp[TT];
  __shared__ int wsum[16];
  __shared__ int mdet;

  // ---- mask layout detection: int32 0/1 => every byte at %4!=0 is zero ----
  if (tid == 0) mdet = 0;
  __syncthreads();
  {
    uchar4 mv = reinterpret_cast<const uchar4*>(mask8)[tid];  // bytes [0,4096)
    if (mv.y | mv.z | mv.w) atomicOr(&mdet, 1);
  }
  __syncthreads();
  const bool is_u8 = (mdet != 0);

  // ---- stage masked preds for this batch ----
  int4 pv = reinterpret_cast<const int4*>(preds_raw + (size_t)b * TT)[tid];
  int m0, m1, m2, m3;
  if (is_u8) {
    uchar4 mv = reinterpret_cast<const uchar4*>(mask8 + (size_t)b * TT)[tid];
    m0 = mv.x; m1 = mv.y; m2 = mv.z; m3 = mv.w;
  } else {
    int4 mv = reinterpret_cast<const int4*>(mask32 + (size_t)b * TT)[tid];
    m0 = mv.x; m1 = mv.y; m2 = mv.z; m3 = mv.w;
  }
  sp[tid * 4 + 0] = m0 ? -1 : pv.x;
  sp[tid * 4 + 1] = m1 ? -1 : pv.y;
  sp[tid * 4 + 2] = m2 ? -1 : pv.z;
  sp[tid * 4 + 3] = m3 ? -1 : pv.w;
  __syncthreads();

  // ---- kept-segment-start flags for my 4 positions ----
  int kb[4]; int cnt = 0;
  #pragma unroll
  for (int j = 0; j < 4; ++j) {
    int t = tid * 4 + j;
    int p = sp[t];
    int isStart = (p != -1) && (t == 0 || p != sp[t - 1]);
    kb[j] = isStart;
    cnt += isStart;
  }

  // ---- 2-level exclusive scan: intra-wave shfl_up, then 16 wave totals ----
  int inc = cnt;
  #pragma unroll
  for (int off = 1; off < 64; off <<= 1) {
    int v = __shfl_up(inc, off);
    if (lane >= off) inc += v;
  }
  if (lane == 63) wsum[wid] = inc;
  __syncthreads();
  int woff = 0, total = 0;
  #pragma unroll
  for (int i = 0; i < 16; ++i) {
    int w = wsum[i];
    if (i < wid) woff += w;
    total += w;
  }
  int k = woff + (inc - cnt);            // exclusive prefix -> my first dest

  // ---- emit seg_info for kept segments I own ----
  #pragma unroll
  for (int j = 0; j < 4; ++j) {
    if (kb[j]) {
      int t = tid * 4 + j;
      int p = sp[t];
      int len = 1;
      while (t + len < TT && sp[t + len] == p) ++len;
      seg_info[(size_t)b * TT + k] = (uint32_t)t | ((uint32_t)len << 16);
      ++k;
    }
  }

  if (tid == 0) n_keep[b] = total;

  // ---- new_pad output: t >= n_keep -> 1.0f else 0.0f ----
  f32x4 pw;
  int t0 = tid * 4;
  pw.x = (t0 + 0 >= total) ? 1.0f : 0.0f;
  pw.y = (t0 + 1 >= total) ? 1.0f : 0.0f;
  pw.z = (t0 + 2 >= total) ? 1.0f : 0.0f;
  pw.w = (t0 + 3 >= total) ? 1.0f : 0.0f;
  __builtin_nontemporal_store(pw, reinterpret_cast<f32x4*>(pad_out + (size_t)b * TT) + tid);
}

// ---------------------------------------------------------------------------
// Kernel C: segment means scattered to compacted rows; zeros elsewhere.
// Grid-stride, 1 wave per output row, 4 rows unrolled (independent dependent-
// load chains; same batch per quad). Non-temporal output stores keep logits
// resident in L3 for the gather.
// ---------------------------------------------------------------------------
__global__ __launch_bounds__(256) void mean_kernel(
    const float* __restrict__ logits,
    const uint32_t* __restrict__ seg_info,
    const int* __restrict__ n_keep,
    float* __restrict__ out) {
  const int lane   = threadIdx.x & 63;
  const int gwave  = (int)((blockIdx.x * blockDim.x + threadIdx.x) >> 6);
  const int nwaves = (int)((gridDim.x * blockDim.x) >> 6);   // 8192

  for (int row = gwave * 4; row < BT; row += nwaves * 4) {
    // row % 4 == 0 and TT % 4 == 0 -> all 4 rows share a batch
    const int b  = row >> 12;
    const int nk = n_keep[b];
    const int kbase = row & (TT - 1);

    uint32_t info[4];
    #pragma unroll
    for (int r = 0; r < 4; ++r)
      info[r] = (kbase + r < nk) ? seg_info[row + r] : 0u;

    f32x4 res[4];
    #pragma unroll
    for (int r = 0; r < 4; ++r) {
      res[r] = (f32x4)0.0f;
      if (kbase + r < nk) {
        int start = (int)(info[r] & 0xFFFFu), len = (int)(info[r] >> 16);
        const float4* g =
            reinterpret_cast<const float4*>(logits + ((size_t)b * TT + start) * CC) + lane;
        float4 s = make_float4(0.f, 0.f, 0.f, 0.f);
        for (int j = 0; j < len; ++j) {
          float4 vv = g[(size_t)j * (CC / 4)];
          s.x += vv.x; s.y += vv.y; s.z += vv.z; s.w += vv.w;
        }
        float inv = 1.0f / (float)len;
        res[r].x = s.x * inv; res[r].y = s.y * inv;
        res[r].z = s.z * inv; res[r].w = s.w * inv;
      }
    }

    #pragma unroll
    for (int r = 0; r < 4; ++r)
      __builtin_nontemporal_store(res[r],
          reinterpret_cast<f32x4*>(out + (size_t)(row + r) * CC) + lane);
  }
}

// ---------------------------------------------------------------------------
extern "C" void kernel_launch(void* const* d_in, const int* in_sizes, int n_in,
                              void* d_out, int out_size, void* d_ws, size_t ws_size,
                              hipStream_t stream) {
  const float* logits        = (const float*)d_in[0];
  const unsigned char* mask8 = (const unsigned char*)d_in[1];
  const int* mask32          = (const int*)d_in[1];

  float* out_logits = (float*)d_out;                       // [B,T,C]
  float* out_pad    = (float*)d_out + (size_t)BT * CC;     // [B,T] as float 0/1

  // workspace layout
  int*      preds    = (int*)d_ws;                               // B*T int32
  uint32_t* seg_info = (uint32_t*)((char*)d_ws + (size_t)BT*4);  // B*T u32
  int*      nkeep    = (int*)((char*)d_ws + (size_t)BT*8);       // B int32

  argmax_kernel<<<NBLK, 256, 0, stream>>>(logits, preds);
  seg_kernel<<<BB, 1024, 0, stream>>>(preds, mask8, mask32, seg_info, nkeep, out_pad);
  mean_kernel<<<NBLK, 256, 0, stream>>>(logits, seg_info, nkeep, out_logits);
}